// Round 20
// baseline (106.956 us; speedup 1.0000x reference)
//
#include <hip/hip_runtime.h>

#define D 64
#define NBMAX 256          // coarse buckets of 512 nodes; supports N <= 131072
#define CAP 8192           // per-bucket region capacity (max observed ~6.5k for E=1.2M)
#define TILE 4096          // binA tile; large tile amortizes the fixed 256-bin scan cost (R14 lesson)
#define PREPB 32           // prep blocks (32 x 512 = 16384 = 256*64 WcT entries)

typedef __attribute__((ext_vector_type(8))) short bf16x8;
typedef __attribute__((ext_vector_type(4))) float f32x4;
typedef __attribute__((ext_vector_type(2))) float f32x2;

// f32 -> bf16 bits, round-to-nearest-even
__device__ __forceinline__ unsigned f2bfu(float f) {
    unsigned u = __float_as_uint(f);
    return (u + 0x7fffu + ((u >> 16) & 1u)) >> 16;
}
__device__ __forceinline__ short f2bf(float f) { return (short)f2bfu(f); }

// ---------------- K0: blocks [0,PREPB): prep WcT/bcat ; [PREPB,+ntiles): binA tile-sort ----------------
// tailcnt is RELATIVE (memset-0) so binA blocks have no ordering dependency on
// prep blocks (block execution order within a kernel is undefined).
__global__ void k_binA(const float* __restrict__ Wq, const float* __restrict__ bq,
                       const float* __restrict__ Wk, const float* __restrict__ bk,
                       const float* __restrict__ Wv, const float* __restrict__ bv,
                       const float* __restrict__ Ws, const float* __restrict__ bs,
                       short* __restrict__ WcT, float* __restrict__ bcat,
                       const int* __restrict__ src, const int* __restrict__ dst,
                       int* __restrict__ tailcnt, unsigned* __restrict__ binned, int E) {
    int tid = threadIdx.x;                      // 512 threads
    if ((int)blockIdx.x < PREPB) {
        int gtid = blockIdx.x * 512 + tid;      // < 16384 = 256*64
        int c = gtid >> 6, kk = gtid & 63;
        int m = c >> 6;
        const float* W = (m == 0) ? Wq : (m == 1) ? Wk : (m == 2) ? Wv : Ws;
        WcT[c * D + kk] = f2bf(W[kk * D + (c & 63)]);
        if (kk == 0) {
            const float* b = (m == 0) ? bq : (m == 1) ? bk : (m == 2) ? bv : bs;
            bcat[c] = b[c & 63];
        }
        return;
    }
    __shared__ unsigned s_ent[TILE];            // 16KB
    __shared__ unsigned short s_bkt[TILE];      // 8KB
    __shared__ unsigned s_sorted[TILE];         // 16KB
    __shared__ unsigned short s_bks[TILE];      // 8KB
    __shared__ int hist[NBMAX];                 // 1KB
    __shared__ int lo[NBMAX];                   // 1KB
    __shared__ int gbase[NBMAX];                // 1KB
    __shared__ int sm[NBMAX];                   // 1KB -> 52KB total
    int t0 = ((int)blockIdx.x - PREPB) * TILE;
    int n = min(TILE, E - t0);
    if (tid < NBMAX) hist[tid] = 0;
    __syncthreads();
    for (int i = tid; i < n; i += 512) {
        int s = src[t0 + i], d = dst[t0 + i];
        int b = d >> 9;
        s_ent[i] = ((unsigned)s << 9) | (unsigned)(d & 511);
        s_bkt[i] = (unsigned short)b;
        atomicAdd(&hist[b], 1);
    }
    __syncthreads();
    int hv = 0;
    if (tid < NBMAX) { hv = hist[tid]; sm[tid] = hv; }
    __syncthreads();
#pragma unroll
    for (int off = 1; off < NBMAX; off <<= 1) {
        int t = (tid >= off && tid < NBMAX) ? sm[tid - off] : 0;
        __syncthreads();
        if (tid < NBMAX) sm[tid] += t;
        __syncthreads();
    }
    if (tid < NBMAX) {
        lo[tid] = sm[tid] - hv;
        if (hv > 0) gbase[tid] = tid * CAP + atomicAdd(&tailcnt[tid], hv);
        hist[tid] = 0;                          // reuse as running index
    }
    __syncthreads();
    for (int i = tid; i < n; i += 512) {
        int b = s_bkt[i];
        int idx = atomicAdd(&hist[b], 1);
        int slot = lo[b] + idx;
        s_sorted[slot] = s_ent[i];
        s_bks[slot] = (unsigned short)b;
    }
    __syncthreads();
    for (int i = tid; i < n; i += 512) {
        int b = s_bks[i];
        binned[gbase[b] + (i - lo[b])] = s_sorted[i];  // contiguous runs per bucket region
    }
}

// ---------------- K1: FAT — blocks [0,NB): binB ; [NB, NB+mb): MFMA GEMM ----------------
// kv packed fp8 e4m3: per dim one (k,v) byte pair -> 2B/dim, 128B/node.
__global__ void k_fat(const unsigned* __restrict__ binned, const int* __restrict__ tailcnt,
                      int* __restrict__ srcs, int* __restrict__ start,
                      int* __restrict__ cnt, int NB,
                      const float* __restrict__ x, const short* __restrict__ WcT,
                      const float* __restrict__ bcat, float* __restrict__ q,
                      unsigned short* __restrict__ kvh16, float* __restrict__ outp, int N) {
    __shared__ int hist[512];   // 2KB
    __shared__ int lo[512];     // 2KB
    __shared__ int sm[256];     // 1KB
    int tid = threadIdx.x;

    if ((int)blockIdx.x < NB) {
        // ---- binB: per coarse bucket, build fine CSR (srcs + start + cnt) ----
        int b = blockIdx.x;
        int e0 = b * CAP, e1 = e0 + tailcnt[b];
        int node0 = b << 9;
        hist[tid] = 0; hist[tid + 256] = 0;
        __syncthreads();
        for (int i = e0 + tid; i < e1; i += 256)
            atomicAdd(&hist[binned[i] & 511], 1);
        __syncthreads();
        int v0 = hist[2 * tid], v1 = hist[2 * tid + 1];
        int ps = v0 + v1;
        sm[tid] = ps;
        __syncthreads();
#pragma unroll
        for (int off = 1; off < 256; off <<= 1) {
            int t = (tid >= off) ? sm[tid - off] : 0;
            __syncthreads();
            sm[tid] += t;
            __syncthreads();
        }
        int excl = sm[tid] - ps;
        lo[2 * tid] = excl;
        lo[2 * tid + 1] = excl + v0;
        int n0 = node0 + 2 * tid;
        if (n0 < N)     { start[n0] = e0 + excl;          cnt[n0] = v0; }
        if (n0 + 1 < N) { start[n0 + 1] = e0 + excl + v0; cnt[n0 + 1] = v1; }
        hist[tid] = 0; hist[tid + 256] = 0;
        __syncthreads();
        for (int i = e0 + tid; i < e1; i += 256) {
            unsigned ent = binned[i];
            int dl = ent & 511;
            int idx = atomicAdd(&hist[dl], 1);
            srcs[e0 + lo[dl] + idx] = (int)(ent >> 9);  // CU-exclusive region
        }
        return;
    }

    // ---- MFMA GEMM: [N,64] x [64,256] -> q (f32) | kv (packed fp8) | skip (f32) ----
    int bid = (int)blockIdx.x - NB;
    int lane = tid & 63;
    int w = tid >> 6;
    int trow = bid * 64 + w * 16;
    int arow = trow + (lane & 15);
    int kbase = (lane >> 4) * 8;

    bf16x8 a0, a1;
    if (arow < N) {
        const float* xr = x + (size_t)arow * D;
        float4 f0 = *(const float4*)(xr + kbase);
        float4 f1 = *(const float4*)(xr + kbase + 4);
        float4 f2 = *(const float4*)(xr + 32 + kbase);
        float4 f3 = *(const float4*)(xr + 32 + kbase + 4);
        a0 = (bf16x8){f2bf(f0.x), f2bf(f0.y), f2bf(f0.z), f2bf(f0.w),
                      f2bf(f1.x), f2bf(f1.y), f2bf(f1.z), f2bf(f1.w)};
        a1 = (bf16x8){f2bf(f2.x), f2bf(f2.y), f2bf(f2.z), f2bf(f2.w),
                      f2bf(f3.x), f2bf(f3.y), f2bf(f3.z), f2bf(f3.w)};
    } else {
        a0 = (bf16x8){0, 0, 0, 0, 0, 0, 0, 0};
        a1 = (bf16x8){0, 0, 0, 0, 0, 0, 0, 0};
    }

    int l15 = lane & 15;
    int rbase = trow + ((lane >> 4) << 2);

#pragma unroll
    for (int g = 0; g < 2; ++g) {
        int ctbase = (g == 0) ? 0 : 12;
        float* dstp = (g == 0) ? q : outp;
#pragma unroll
        for (int j = 0; j < 4; ++j) {
            int col = (ctbase + j) * 16 + l15;
            const short* wr = WcT + col * D + kbase;
            bf16x8 b0 = *(const bf16x8*)(wr);
            bf16x8 b1 = *(const bf16x8*)(wr + 32);
            f32x4 acc = {0.f, 0.f, 0.f, 0.f};
            acc = __builtin_amdgcn_mfma_f32_16x16x32_bf16(a0, b0, acc, 0, 0, 0);
            acc = __builtin_amdgcn_mfma_f32_16x16x32_bf16(a1, b1, acc, 0, 0, 0);
            float bias = bcat[col];
            int cmod = col & 63;
#pragma unroll
            for (int r = 0; r < 4; ++r) {
                int row = rbase + r;
                if (row < N) dstp[(size_t)row * D + cmod] = acc[r] + bias;
            }
        }
    }
#pragma unroll
    for (int j = 0; j < 4; ++j) {
        int kcol = (4 + j) * 16 + l15;
        int vcol = (8 + j) * 16 + l15;
        const short* wrk = WcT + kcol * D + kbase;
        const short* wrv = WcT + vcol * D + kbase;
        bf16x8 bk0 = *(const bf16x8*)(wrk);
        bf16x8 bk1 = *(const bf16x8*)(wrk + 32);
        bf16x8 bv0 = *(const bf16x8*)(wrv);
        bf16x8 bv1 = *(const bf16x8*)(wrv + 32);
        f32x4 ak = {0.f, 0.f, 0.f, 0.f}, av = {0.f, 0.f, 0.f, 0.f};
        ak = __builtin_amdgcn_mfma_f32_16x16x32_bf16(a0, bk0, ak, 0, 0, 0);
        ak = __builtin_amdgcn_mfma_f32_16x16x32_bf16(a1, bk1, ak, 0, 0, 0);
        av = __builtin_amdgcn_mfma_f32_16x16x32_bf16(a0, bv0, av, 0, 0, 0);
        av = __builtin_amdgcn_mfma_f32_16x16x32_bf16(a1, bv1, av, 0, 0, 0);
        float biask = bcat[kcol], biasv = bcat[vcol];
        int cmod = kcol & 63;
#pragma unroll
        for (int r = 0; r < 4; ++r) {
            int row = rbase + r;
            if (row < N) {
                // pack (k,v) as fp8 e4m3 pair -> 2 bytes per dim
                unsigned pw = __builtin_amdgcn_cvt_pk_fp8_f32(ak[r] + biask, av[r] + biasv, 0, false);
                kvh16[(size_t)row * D + cmod] = (unsigned short)pw;
            }
        }
    }
}

// ---------------- K2: fused attention + skip + relu ----------------
// One wave per node, 4 groups of 16 lanes, 4 edges per group per iteration.
// kv gathered as uint2 (8B = 4 dims x fp8(k,v) pairs); q prescale folds
// 1/sqrt(64) * log2(e) so exp2f needs no per-edge multiply.
__global__ void k_fused(const int* __restrict__ srcs, const int* __restrict__ start,
                        const int* __restrict__ cnt,
                        const float* __restrict__ q, const uint2* __restrict__ kv2,
                        float* __restrict__ out, int N) {
    int wid = (int)((blockIdx.x * (size_t)blockDim.x + threadIdx.x) >> 6);
    int lane = threadIdx.x & 63;
    if (wid >= N) return;
    int g = lane >> 4, j = lane & 15;
    int s0 = start[wid];
    int c  = cnt[wid];
    int s1 = s0 + c;
    size_t qo = (size_t)wid * D + j * 4;
    float4 qv = *(const float4*)(q + qo);
    const float PS = 0.125f * 1.44269504088896340736f;  // 1/sqrt(D) * log2(e)
    qv.x *= PS; qv.y *= PS; qv.z *= PS; qv.w *= PS;
    float a0 = 0.f, a1 = 0.f, a2 = 0.f, a3 = 0.f, l = 0.f;
    for (int t = s0; t < s1; t += 16) {
        int eA = t + g, eB = t + 4 + g, eC = t + 8 + g, eD = t + 12 + g;
        int iA = min(eA, s1 - 1), iB = min(eB, s1 - 1);
        int iC = min(eC, s1 - 1), iD = min(eD, s1 - 1);
        int sjA = srcs[iA], sjB = srcs[iB], sjC = srcs[iC], sjD = srcs[iD];
        uint2 uA = kv2[(size_t)sjA * 16 + j];
        uint2 uB = kv2[(size_t)sjB * 16 + j];
        uint2 uC = kv2[(size_t)sjC * 16 + j];
        uint2 uD = kv2[(size_t)sjD * 16 + j];
        f32x2 A0 = __builtin_amdgcn_cvt_pk_f32_fp8(uA.x, false);
        f32x2 A1 = __builtin_amdgcn_cvt_pk_f32_fp8(uA.x, true);
        f32x2 A2 = __builtin_amdgcn_cvt_pk_f32_fp8(uA.y, false);
        f32x2 A3 = __builtin_amdgcn_cvt_pk_f32_fp8(uA.y, true);
        f32x2 B0 = __builtin_amdgcn_cvt_pk_f32_fp8(uB.x, false);
        f32x2 B1 = __builtin_amdgcn_cvt_pk_f32_fp8(uB.x, true);
        f32x2 B2 = __builtin_amdgcn_cvt_pk_f32_fp8(uB.y, false);
        f32x2 B3 = __builtin_amdgcn_cvt_pk_f32_fp8(uB.y, true);
        f32x2 C0 = __builtin_amdgcn_cvt_pk_f32_fp8(uC.x, false);
        f32x2 C1 = __builtin_amdgcn_cvt_pk_f32_fp8(uC.x, true);
        f32x2 C2 = __builtin_amdgcn_cvt_pk_f32_fp8(uC.y, false);
        f32x2 C3 = __builtin_amdgcn_cvt_pk_f32_fp8(uC.y, true);
        f32x2 D0 = __builtin_amdgcn_cvt_pk_f32_fp8(uD.x, false);
        f32x2 D1 = __builtin_amdgcn_cvt_pk_f32_fp8(uD.x, true);
        f32x2 D2 = __builtin_amdgcn_cvt_pk_f32_fp8(uD.y, false);
        f32x2 D3 = __builtin_amdgcn_cvt_pk_f32_fp8(uD.y, true);
        float pA, pB, pC, pD;
        pA = A0.x * qv.x;
        pA = fmaf(A1.x, qv.y, pA);
        pA = fmaf(A2.x, qv.z, pA);
        pA = fmaf(A3.x, qv.w, pA);
        pB = B0.x * qv.x;
        pB = fmaf(B1.x, qv.y, pB);
        pB = fmaf(B2.x, qv.z, pB);
        pB = fmaf(B3.x, qv.w, pB);
        pC = C0.x * qv.x;
        pC = fmaf(C1.x, qv.y, pC);
        pC = fmaf(C2.x, qv.z, pC);
        pC = fmaf(C3.x, qv.w, pC);
        pD = D0.x * qv.x;
        pD = fmaf(D1.x, qv.y, pD);
        pD = fmaf(D2.x, qv.z, pD);
        pD = fmaf(D3.x, qv.w, pD);
#pragma unroll
        for (int off = 1; off < 16; off <<= 1) {
            pA += __shfl_xor(pA, off, 64);
            pB += __shfl_xor(pB, off, 64);
            pC += __shfl_xor(pC, off, 64);
            pD += __shfl_xor(pD, off, 64);
        }
        float eAf = (eA < s1) ? exp2f(pA) : 0.f;
        float eBf = (eB < s1) ? exp2f(pB) : 0.f;
        float eCf = (eC < s1) ? exp2f(pC) : 0.f;
        float eDf = (eD < s1) ? exp2f(pD) : 0.f;
        l += (eAf + eBf) + (eCf + eDf);
        a0 = fmaf(eAf, A0.y, a0);
        a1 = fmaf(eAf, A1.y, a1);
        a2 = fmaf(eAf, A2.y, a2);
        a3 = fmaf(eAf, A3.y, a3);
        a0 = fmaf(eBf, B0.y, a0);
        a1 = fmaf(eBf, B1.y, a1);
        a2 = fmaf(eBf, B2.y, a2);
        a3 = fmaf(eBf, B3.y, a3);
        a0 = fmaf(eCf, C0.y, a0);
        a1 = fmaf(eCf, C1.y, a1);
        a2 = fmaf(eCf, C2.y, a2);
        a3 = fmaf(eCf, C3.y, a3);
        a0 = fmaf(eDf, D0.y, a0);
        a1 = fmaf(eDf, D1.y, a1);
        a2 = fmaf(eDf, D2.y, a2);
        a3 = fmaf(eDf, D3.y, a3);
    }
    // combine the 4 groups (lanes with same j hold the same dims)
#pragma unroll
    for (int off = 16; off < 64; off <<= 1) {
        a0 += __shfl_xor(a0, off, 64);
        a1 += __shfl_xor(a1, off, 64);
        a2 += __shfl_xor(a2, off, 64);
        a3 += __shfl_xor(a3, off, 64);
        l  += __shfl_xor(l,  off, 64);
    }
    if (g == 0) {
        float inv = (c > 0) ? 1.f / l : 0.f;
        float4 sk = *(const float4*)(out + qo);
        float4 r;
        r.x = fmaxf(fmaf(a0, inv, sk.x), 0.f);
        r.y = fmaxf(fmaf(a1, inv, sk.y), 0.f);
        r.z = fmaxf(fmaf(a2, inv, sk.z), 0.f);
        r.w = fmaxf(fmaf(a3, inv, sk.w), 0.f);
        *(float4*)(out + qo) = r;
    }
}

extern "C" void kernel_launch(void* const* d_in, const int* in_sizes, int n_in,
                              void* d_out, int out_size, void* d_ws, size_t ws_size,
                              hipStream_t stream) {
    const float* x  = (const float*)d_in[0];
    const int*   ei = (const int*)d_in[1];
    const float* Wq = (const float*)d_in[2]; const float* bq = (const float*)d_in[3];
    const float* Wk = (const float*)d_in[4]; const float* bk = (const float*)d_in[5];
    const float* Wv = (const float*)d_in[6]; const float* bv = (const float*)d_in[7];
    const float* Ws = (const float*)d_in[8]; const float* bs = (const float*)d_in[9];

    int N = in_sizes[0] / D;
    int E = in_sizes[1] / 2;
    const int* src = ei;
    const int* dst = ei + E;
    float* out = (float*)d_out;

    int NB = (N + 511) >> 9;   // 196 for N=100000

    // workspace layout; kvh16 = packed fp8 (k,v) pairs, N*64 ushort = N*128 bytes
    float*          q      = (float*)d_ws;
    unsigned short* kvh16  = (unsigned short*)(q + (size_t)N * D);
    unsigned*       binned = (unsigned*)(kvh16 + (size_t)N * D);
    int*            srcs   = (int*)(binned + (size_t)NB * CAP);
    int*            start  = srcs + (size_t)NB * CAP;
    int*            cnt    = start + N;
    int*            tailcnt= cnt + N;                 // NBMAX relative counts (memset 0)
    short*          WcT    = (short*)(tailcnt + NBMAX);
    float*          bcat   = (float*)(WcT + 256 * D);

    hipMemsetAsync(tailcnt, 0, NBMAX * sizeof(int), stream);

    int ntiles = (E + TILE - 1) / TILE;
    k_binA<<<PREPB + ntiles, 512, 0, stream>>>(Wq, bq, Wk, bk, Wv, bv, Ws, bs,
                                               WcT, bcat, src, dst, tailcnt, binned, E);
    int mb = (N + 63) / 64;
    k_fat<<<NB + mb, 256, 0, stream>>>(binned, tailcnt, srcs, start, cnt, NB,
                                       x, WcT, bcat, q, kvh16, out, N);
    k_fused<<<(N + 3) / 4, 256, 0, stream>>>(srcs, start, cnt, q, (const uint2*)kvh16, out, N);
}

// Round 21
// 104.840 us; speedup vs baseline: 1.0202x; 1.0202x over previous
//
#include <hip/hip_runtime.h>

#define D 64
#define NBMAX 256          // coarse buckets of 512 nodes; supports N <= 131072
#define CAP 8192           // per-bucket region capacity (max observed ~6.5k for E=1.2M)
#define TILE 4096          // binA tile; large tile amortizes the fixed 256-bin scan cost (R14 lesson)

typedef __attribute__((ext_vector_type(8))) short bf16x8;
typedef __attribute__((ext_vector_type(4))) float f32x4;
typedef __attribute__((ext_vector_type(2))) float f32x2;

// f32 -> bf16 bits, round-to-nearest-even
__device__ __forceinline__ unsigned f2bfu(float f) {
    unsigned u = __float_as_uint(f);
    return (u + 0x7fffu + ((u >> 16) & 1u)) >> 16;
}
__device__ __forceinline__ short f2bf(float f) { return (short)f2bfu(f); }

// ---------------- K0: prep — WcT[256][64] bf16, bcat[256], strided tail init ----------------
__global__ void k_prep(const float* __restrict__ Wq, const float* __restrict__ bq,
                       const float* __restrict__ Wk, const float* __restrict__ bk,
                       const float* __restrict__ Wv, const float* __restrict__ bv,
                       const float* __restrict__ Ws, const float* __restrict__ bs,
                       short* __restrict__ WcT, float* __restrict__ bcat,
                       int* __restrict__ tail, int NB) {
    int gtid = blockIdx.x * 256 + threadIdx.x;
    if (gtid < 256 * D) {
        int c = gtid >> 6, kk = gtid & 63;
        int m = c >> 6;
        const float* W = (m == 0) ? Wq : (m == 1) ? Wk : (m == 2) ? Wv : Ws;
        WcT[c * D + kk] = f2bf(W[kk * D + (c & 63)]);
        if (kk == 0) {
            const float* b = (m == 0) ? bq : (m == 1) ? bk : (m == 2) ? bv : bs;
            bcat[c] = b[c & 63];
        }
    }
    if (gtid < NB) tail[gtid] = gtid * CAP;
}

// ---------------- Pass A: LDS tile-sort into strided coarse buckets (R15-proven) ----------------
__global__ void k_binA(const int* __restrict__ src, const int* __restrict__ dst,
                       int* __restrict__ tail, unsigned* __restrict__ binned, int E) {
    __shared__ unsigned s_ent[TILE];            // 16KB
    __shared__ unsigned short s_bkt[TILE];      // 8KB
    __shared__ unsigned s_sorted[TILE];         // 16KB
    __shared__ unsigned short s_bks[TILE];      // 8KB
    __shared__ int hist[NBMAX];                 // 1KB
    __shared__ int lo[NBMAX];                   // 1KB
    __shared__ int gbase[NBMAX];                // 1KB
    __shared__ int sm[NBMAX];                   // 1KB -> 52KB total
    int tid = threadIdx.x;                      // 512 threads
    int ntiles = (E + TILE - 1) / TILE;
    for (int tix = blockIdx.x; tix < ntiles; tix += gridDim.x) {
        int t0 = tix * TILE;
        int n = min(TILE, E - t0);
        if (tid < NBMAX) hist[tid] = 0;
        __syncthreads();
        for (int i = tid; i < n; i += 512) {
            int s = src[t0 + i], d = dst[t0 + i];
            int b = d >> 9;
            s_ent[i] = ((unsigned)s << 9) | (unsigned)(d & 511);
            s_bkt[i] = (unsigned short)b;
            atomicAdd(&hist[b], 1);
        }
        __syncthreads();
        int hv = 0;
        if (tid < NBMAX) { hv = hist[tid]; sm[tid] = hv; }
        __syncthreads();
#pragma unroll
        for (int off = 1; off < NBMAX; off <<= 1) {
            int t = (tid >= off && tid < NBMAX) ? sm[tid - off] : 0;
            __syncthreads();
            if (tid < NBMAX) sm[tid] += t;
            __syncthreads();
        }
        if (tid < NBMAX) {
            lo[tid] = sm[tid] - hv;
            if (hv > 0) gbase[tid] = atomicAdd(&tail[tid], hv);
            hist[tid] = 0;                      // reuse as running index
        }
        __syncthreads();
        for (int i = tid; i < n; i += 512) {
            int b = s_bkt[i];
            int idx = atomicAdd(&hist[b], 1);
            int slot = lo[b] + idx;
            s_sorted[slot] = s_ent[i];
            s_bks[slot] = (unsigned short)b;
        }
        __syncthreads();
        for (int i = tid; i < n; i += 512) {
            int b = s_bks[i];
            binned[gbase[b] + (i - lo[b])] = s_sorted[i];  // contiguous runs per bucket region
        }
        __syncthreads();
    }
}

// ---------------- K1: FAT — blocks [0,NB): binB ; [NB, NB+mb): MFMA GEMM ----------------
// kv packed fp8 e4m3: per dim one (k,v) byte pair -> 2B/dim, 128B/node.
__global__ void k_fat(const unsigned* __restrict__ binned, const int* __restrict__ tail,
                      int* __restrict__ srcs, int* __restrict__ start,
                      int* __restrict__ cnt, int NB,
                      const float* __restrict__ x, const short* __restrict__ WcT,
                      const float* __restrict__ bcat, float* __restrict__ q,
                      unsigned short* __restrict__ kvh16, float* __restrict__ outp, int N) {
    __shared__ int hist[512];   // 2KB
    __shared__ int lo[512];     // 2KB
    __shared__ int sm[256];     // 1KB
    int tid = threadIdx.x;

    if ((int)blockIdx.x < NB) {
        // ---- binB: per coarse bucket, build fine CSR (srcs + start + cnt) ----
        int b = blockIdx.x;
        int e0 = b * CAP, e1 = tail[b];
        int node0 = b << 9;
        hist[tid] = 0; hist[tid + 256] = 0;
        __syncthreads();
        for (int i = e0 + tid; i < e1; i += 256)
            atomicAdd(&hist[binned[i] & 511], 1);
        __syncthreads();
        int v0 = hist[2 * tid], v1 = hist[2 * tid + 1];
        int ps = v0 + v1;
        sm[tid] = ps;
        __syncthreads();
#pragma unroll
        for (int off = 1; off < 256; off <<= 1) {
            int t = (tid >= off) ? sm[tid - off] : 0;
            __syncthreads();
            sm[tid] += t;
            __syncthreads();
        }
        int excl = sm[tid] - ps;
        lo[2 * tid] = excl;
        lo[2 * tid + 1] = excl + v0;
        int n0 = node0 + 2 * tid;
        if (n0 < N)     { start[n0] = e0 + excl;          cnt[n0] = v0; }
        if (n0 + 1 < N) { start[n0 + 1] = e0 + excl + v0; cnt[n0 + 1] = v1; }
        hist[tid] = 0; hist[tid + 256] = 0;
        __syncthreads();
        for (int i = e0 + tid; i < e1; i += 256) {
            unsigned ent = binned[i];
            int dl = ent & 511;
            int idx = atomicAdd(&hist[dl], 1);
            srcs[e0 + lo[dl] + idx] = (int)(ent >> 9);  // CU-exclusive region
        }
        return;
    }

    // ---- MFMA GEMM: [N,64] x [64,256] -> q (f32) | kv (packed fp8) | skip (f32) ----
    int bid = (int)blockIdx.x - NB;
    int lane = tid & 63;
    int w = tid >> 6;
    int trow = bid * 64 + w * 16;
    int arow = trow + (lane & 15);
    int kbase = (lane >> 4) * 8;

    bf16x8 a0, a1;
    if (arow < N) {
        const float* xr = x + (size_t)arow * D;
        float4 f0 = *(const float4*)(xr + kbase);
        float4 f1 = *(const float4*)(xr + kbase + 4);
        float4 f2 = *(const float4*)(xr + 32 + kbase);
        float4 f3 = *(const float4*)(xr + 32 + kbase + 4);
        a0 = (bf16x8){f2bf(f0.x), f2bf(f0.y), f2bf(f0.z), f2bf(f0.w),
                      f2bf(f1.x), f2bf(f1.y), f2bf(f1.z), f2bf(f1.w)};
        a1 = (bf16x8){f2bf(f2.x), f2bf(f2.y), f2bf(f2.z), f2bf(f2.w),
                      f2bf(f3.x), f2bf(f3.y), f2bf(f3.z), f2bf(f3.w)};
    } else {
        a0 = (bf16x8){0, 0, 0, 0, 0, 0, 0, 0};
        a1 = (bf16x8){0, 0, 0, 0, 0, 0, 0, 0};
    }

    int l15 = lane & 15;
    int rbase = trow + ((lane >> 4) << 2);

#pragma unroll
    for (int g = 0; g < 2; ++g) {
        int ctbase = (g == 0) ? 0 : 12;
        float* dstp = (g == 0) ? q : outp;
#pragma unroll
        for (int j = 0; j < 4; ++j) {
            int col = (ctbase + j) * 16 + l15;
            const short* wr = WcT + col * D + kbase;
            bf16x8 b0 = *(const bf16x8*)(wr);
            bf16x8 b1 = *(const bf16x8*)(wr + 32);
            f32x4 acc = {0.f, 0.f, 0.f, 0.f};
            acc = __builtin_amdgcn_mfma_f32_16x16x32_bf16(a0, b0, acc, 0, 0, 0);
            acc = __builtin_amdgcn_mfma_f32_16x16x32_bf16(a1, b1, acc, 0, 0, 0);
            float bias = bcat[col];
            int cmod = col & 63;
#pragma unroll
            for (int r = 0; r < 4; ++r) {
                int row = rbase + r;
                if (row < N) dstp[(size_t)row * D + cmod] = acc[r] + bias;
            }
        }
    }
#pragma unroll
    for (int j = 0; j < 4; ++j) {
        int kcol = (4 + j) * 16 + l15;
        int vcol = (8 + j) * 16 + l15;
        const short* wrk = WcT + kcol * D + kbase;
        const short* wrv = WcT + vcol * D + kbase;
        bf16x8 bk0 = *(const bf16x8*)(wrk);
        bf16x8 bk1 = *(const bf16x8*)(wrk + 32);
        bf16x8 bv0 = *(const bf16x8*)(wrv);
        bf16x8 bv1 = *(const bf16x8*)(wrv + 32);
        f32x4 ak = {0.f, 0.f, 0.f, 0.f}, av = {0.f, 0.f, 0.f, 0.f};
        ak = __builtin_amdgcn_mfma_f32_16x16x32_bf16(a0, bk0, ak, 0, 0, 0);
        ak = __builtin_amdgcn_mfma_f32_16x16x32_bf16(a1, bk1, ak, 0, 0, 0);
        av = __builtin_amdgcn_mfma_f32_16x16x32_bf16(a0, bv0, av, 0, 0, 0);
        av = __builtin_amdgcn_mfma_f32_16x16x32_bf16(a1, bv1, av, 0, 0, 0);
        float biask = bcat[kcol], biasv = bcat[vcol];
        int cmod = kcol & 63;
#pragma unroll
        for (int r = 0; r < 4; ++r) {
            int row = rbase + r;
            if (row < N) {
                // pack (k,v) as fp8 e4m3 pair -> 2 bytes per dim
                unsigned pw = __builtin_amdgcn_cvt_pk_fp8_f32(ak[r] + biask, av[r] + biasv, 0, false);
                kvh16[(size_t)row * D + cmod] = (unsigned short)pw;
            }
        }
    }
}

// ---------------- K2: fused attention + skip + relu ----------------
// One wave per node, 4 groups of 16 lanes, 4 edges per group per iteration.
// kv gathered as uint2 (8B = 4 dims x fp8(k,v) pairs), HW cvt_pk_f32_fp8 unpack.
__global__ void k_fused(const int* __restrict__ srcs, const int* __restrict__ start,
                        const int* __restrict__ cnt,
                        const float* __restrict__ q, const uint2* __restrict__ kv2,
                        float* __restrict__ out, int N) {
    int wid = (int)((blockIdx.x * (size_t)blockDim.x + threadIdx.x) >> 6);
    int lane = threadIdx.x & 63;
    if (wid >= N) return;
    int g = lane >> 4, j = lane & 15;
    int s0 = start[wid];
    int c  = cnt[wid];
    int s1 = s0 + c;
    size_t qo = (size_t)wid * D + j * 4;
    float4 qv = *(const float4*)(q + qo);
    qv.x *= 0.125f; qv.y *= 0.125f; qv.z *= 0.125f; qv.w *= 0.125f;
    float a0 = 0.f, a1 = 0.f, a2 = 0.f, a3 = 0.f, l = 0.f;
    for (int t = s0; t < s1; t += 16) {
        int eA = t + g, eB = t + 4 + g, eC = t + 8 + g, eD = t + 12 + g;
        int iA = min(eA, s1 - 1), iB = min(eB, s1 - 1);
        int iC = min(eC, s1 - 1), iD = min(eD, s1 - 1);
        int sjA = srcs[iA], sjB = srcs[iB], sjC = srcs[iC], sjD = srcs[iD];
        uint2 uA = kv2[(size_t)sjA * 16 + j];
        uint2 uB = kv2[(size_t)sjB * 16 + j];
        uint2 uC = kv2[(size_t)sjC * 16 + j];
        uint2 uD = kv2[(size_t)sjD * 16 + j];
        // unpack: word lo16 = dim (k,v), hi16 = next dim (k,v)
        f32x2 A0 = __builtin_amdgcn_cvt_pk_f32_fp8(uA.x, false);
        f32x2 A1 = __builtin_amdgcn_cvt_pk_f32_fp8(uA.x, true);
        f32x2 A2 = __builtin_amdgcn_cvt_pk_f32_fp8(uA.y, false);
        f32x2 A3 = __builtin_amdgcn_cvt_pk_f32_fp8(uA.y, true);
        f32x2 B0 = __builtin_amdgcn_cvt_pk_f32_fp8(uB.x, false);
        f32x2 B1 = __builtin_amdgcn_cvt_pk_f32_fp8(uB.x, true);
        f32x2 B2 = __builtin_amdgcn_cvt_pk_f32_fp8(uB.y, false);
        f32x2 B3 = __builtin_amdgcn_cvt_pk_f32_fp8(uB.y, true);
        f32x2 C0 = __builtin_amdgcn_cvt_pk_f32_fp8(uC.x, false);
        f32x2 C1 = __builtin_amdgcn_cvt_pk_f32_fp8(uC.x, true);
        f32x2 C2 = __builtin_amdgcn_cvt_pk_f32_fp8(uC.y, false);
        f32x2 C3 = __builtin_amdgcn_cvt_pk_f32_fp8(uC.y, true);
        f32x2 D0 = __builtin_amdgcn_cvt_pk_f32_fp8(uD.x, false);
        f32x2 D1 = __builtin_amdgcn_cvt_pk_f32_fp8(uD.x, true);
        f32x2 D2 = __builtin_amdgcn_cvt_pk_f32_fp8(uD.y, false);
        f32x2 D3 = __builtin_amdgcn_cvt_pk_f32_fp8(uD.y, true);
        float pA, pB, pC, pD;
        pA = A0.x * qv.x;
        pA = fmaf(A1.x, qv.y, pA);
        pA = fmaf(A2.x, qv.z, pA);
        pA = fmaf(A3.x, qv.w, pA);
        pB = B0.x * qv.x;
        pB = fmaf(B1.x, qv.y, pB);
        pB = fmaf(B2.x, qv.z, pB);
        pB = fmaf(B3.x, qv.w, pB);
        pC = C0.x * qv.x;
        pC = fmaf(C1.x, qv.y, pC);
        pC = fmaf(C2.x, qv.z, pC);
        pC = fmaf(C3.x, qv.w, pC);
        pD = D0.x * qv.x;
        pD = fmaf(D1.x, qv.y, pD);
        pD = fmaf(D2.x, qv.z, pD);
        pD = fmaf(D3.x, qv.w, pD);
#pragma unroll
        for (int off = 1; off < 16; off <<= 1) {
            pA += __shfl_xor(pA, off, 64);
            pB += __shfl_xor(pB, off, 64);
            pC += __shfl_xor(pC, off, 64);
            pD += __shfl_xor(pD, off, 64);
        }
        float eAf = (eA < s1) ? __expf(pA) : 0.f;
        float eBf = (eB < s1) ? __expf(pB) : 0.f;
        float eCf = (eC < s1) ? __expf(pC) : 0.f;
        float eDf = (eD < s1) ? __expf(pD) : 0.f;
        l += (eAf + eBf) + (eCf + eDf);
        a0 = fmaf(eAf, A0.y, a0);
        a1 = fmaf(eAf, A1.y, a1);
        a2 = fmaf(eAf, A2.y, a2);
        a3 = fmaf(eAf, A3.y, a3);
        a0 = fmaf(eBf, B0.y, a0);
        a1 = fmaf(eBf, B1.y, a1);
        a2 = fmaf(eBf, B2.y, a2);
        a3 = fmaf(eBf, B3.y, a3);
        a0 = fmaf(eCf, C0.y, a0);
        a1 = fmaf(eCf, C1.y, a1);
        a2 = fmaf(eCf, C2.y, a2);
        a3 = fmaf(eCf, C3.y, a3);
        a0 = fmaf(eDf, D0.y, a0);
        a1 = fmaf(eDf, D1.y, a1);
        a2 = fmaf(eDf, D2.y, a2);
        a3 = fmaf(eDf, D3.y, a3);
    }
    // combine the 4 groups (lanes with same j hold the same dims)
#pragma unroll
    for (int off = 16; off < 64; off <<= 1) {
        a0 += __shfl_xor(a0, off, 64);
        a1 += __shfl_xor(a1, off, 64);
        a2 += __shfl_xor(a2, off, 64);
        a3 += __shfl_xor(a3, off, 64);
        l  += __shfl_xor(l,  off, 64);
    }
    if (g == 0) {
        float inv = (c > 0) ? 1.f / l : 0.f;
        float4 sk = *(const float4*)(out + qo);
        float4 r;
        r.x = fmaxf(fmaf(a0, inv, sk.x), 0.f);
        r.y = fmaxf(fmaf(a1, inv, sk.y), 0.f);
        r.z = fmaxf(fmaf(a2, inv, sk.z), 0.f);
        r.w = fmaxf(fmaf(a3, inv, sk.w), 0.f);
        *(float4*)(out + qo) = r;
    }
}

extern "C" void kernel_launch(void* const* d_in, const int* in_sizes, int n_in,
                              void* d_out, int out_size, void* d_ws, size_t ws_size,
                              hipStream_t stream) {
    const float* x  = (const float*)d_in[0];
    const int*   ei = (const int*)d_in[1];
    const float* Wq = (const float*)d_in[2]; const float* bq = (const float*)d_in[3];
    const float* Wk = (const float*)d_in[4]; const float* bk = (const float*)d_in[5];
    const float* Wv = (const float*)d_in[6]; const float* bv = (const float*)d_in[7];
    const float* Ws = (const float*)d_in[8]; const float* bs = (const float*)d_in[9];

    int N = in_sizes[0] / D;
    int E = in_sizes[1] / 2;
    const int* src = ei;
    const int* dst = ei + E;
    float* out = (float*)d_out;

    int NB = (N + 511) >> 9;   // 196 for N=100000

    // workspace layout; kvh16 = packed fp8 (k,v) pairs, N*64 ushort = N*128 bytes
    float*          q      = (float*)d_ws;
    unsigned short* kvh16  = (unsigned short*)(q + (size_t)N * D);
    unsigned*       binned = (unsigned*)(kvh16 + (size_t)N * D);
    int*            srcs   = (int*)(binned + (size_t)NB * CAP);
    int*            start  = srcs + (size_t)NB * CAP;
    int*            cnt    = start + N;
    int*            tail   = cnt + N;                 // NBMAX entries
    short*          WcT    = (short*)(tail + NBMAX);
    float*          bcat   = (float*)(WcT + 256 * D);

    k_prep<<<64, 256, 0, stream>>>(Wq, bq, Wk, bk, Wv, bv, Ws, bs,
                                   WcT, bcat, tail, NB);
    int ntiles = (E + TILE - 1) / TILE;
    k_binA<<<(ntiles < 512 ? ntiles : 512), 512, 0, stream>>>(src, dst, tail, binned, E);
    int mb = (N + 63) / 64;
    k_fat<<<NB + mb, 256, 0, stream>>>(binned, tail, srcs, start, cnt, NB,
                                       x, WcT, bcat, q, kvh16, out, N);
    k_fused<<<(N + 3) / 4, 256, 0, stream>>>(srcs, start, cnt, q, (const uint2*)kvh16, out, N);
}